// Round 1
// 240.711 us; speedup vs baseline: 1.0051x; 1.0051x over previous
//
#include <hip/hip_runtime.h>
#include <math.h>

#define NB 4096
#define PAD 2048
#define BLOCK 256
#define ITERS (NB / 4 / BLOCK)   // 4 float4 iterations per thread

__device__ __forceinline__ int mirror_idx(int i) {
    // valid for i in [-PAD, NB+PAD-2]; single reflection
    i = ::abs(i);
    return (i < NB) ? i : (2 * (NB - 1) - i);
}

// Precompute p = sigmoid(logits), lsp = log_sigmoid(logits), lsn = log_sigmoid(-logits)
// into ws[0..NB), ws[NB..2NB), ws[2NB..3NB).
__global__ void fbmp_precompute(const float* __restrict__ logits, float* __restrict__ ws) {
    int j = blockIdx.x * blockDim.x + threadIdx.x;
    if (j >= NB) return;
    float x = logits[j];
    double xd = (double)x;
    float e = (float)exp(-xd);
    float p = 1.0f / (1.0f + e);
    float lsp = (float)(-log1p(exp(-xd)));  // log_sigmoid(x)
    float lsn = (float)(-log1p(exp(xd)));   // log_sigmoid(-x)
    ws[j] = p;
    ws[NB + j] = lsp;
    ws[2 * NB + j] = lsn;
}

__global__ __launch_bounds__(BLOCK, 8) void fbmp_main(
    const float* __restrict__ u, const int* __restrict__ shift,
    const float* __restrict__ ws,
    float* __restrict__ masks, float* __restrict__ logp)
{
    __shared__ float sg[NB];            // this row's grid bits (as float)
    __shared__ float sred[BLOCK / 64];  // per-wave partial sums

    const int b = blockIdx.x;
    const int s = shift[b] - PAD;       // issue the scalar load early

    const float4* __restrict__ u4   = (const float4*)(u + (size_t)b * NB);
    const float4* __restrict__ p4   = (const float4*)(ws);
    const float4* __restrict__ lsp4 = (const float4*)(ws + NB);
    const float4* __restrict__ lsn4 = (const float4*)(ws + 2 * NB);

    // ---- phase 1: compute grid + log-prob partial, software-pipelined loads ----
    float acc = 0.0f;
    {
        const int t = threadIdx.x;
        float4 uv = u4[t];
        float4 pv = p4[t];
        float4 ap = lsp4[t];
        float4 an = lsn4[t];
        #pragma unroll
        for (int it = 0; it < ITERS; ++it) {
            float4 nuv, npv, nap, nan2;
            if (it + 1 < ITERS) {           // compile-time resolved (full unroll)
                const int i1 = t + (it + 1) * BLOCK;
                nuv = u4[i1];
                npv = p4[i1];
                nap = lsp4[i1];
                nan2 = lsn4[i1];
            }
            const int i = t + it * BLOCK;
            bool c0 = uv.x < pv.x;
            bool c1 = uv.y < pv.y;
            bool c2 = uv.z < pv.z;
            bool c3 = uv.w < pv.w;
            // identical select + association order as the verified kernel
            acc += (c0 ? ap.x : an.x) + (c1 ? ap.y : an.y)
                 + (c2 ? ap.z : an.z) + (c3 ? ap.w : an.w);
            float4 g;
            g.x = c0 ? 1.0f : 0.0f;
            g.y = c1 ? 1.0f : 0.0f;
            g.z = c2 ? 1.0f : 0.0f;
            g.w = c3 ? 1.0f : 0.0f;
            ((float4*)sg)[i] = g;
            uv = nuv; pv = npv; ap = nap; an = nan2;
        }
    }

    // ---- block reduction of acc -> logp[b] (unchanged tree) ----
    #pragma unroll
    for (int off = 32; off > 0; off >>= 1)
        acc += __shfl_down(acc, off, 64);
    const int lane = threadIdx.x & 63;
    const int wid  = threadIdx.x >> 6;
    if (lane == 0) sred[wid] = acc;
    __syncthreads();   // also publishes sg for the gather below
    if (threadIdx.x == 0) {
        float t = 0.0f;
        #pragma unroll
        for (int w = 0; w < BLOCK / 64; ++w) t += sred[w];
        logp[b] = t;
    }

    // ---- phase 2: reflect-pad shifted-window gather ----
    // Thread t handles k = t + j*BLOCK: lane-stride-1 LDS reads (conflict-free,
    // 2 lanes/bank) instead of the old stride-4 float4 gather (8-way conflict).
    // Stores are 4 B/lane but 256 B contiguous per wave -> fully coalesced.
    // Nontemporal: masks is write-once-never-read; keep L3 for u.
    float* __restrict__ mrow = masks + (size_t)b * NB;
    #pragma unroll
    for (int it = 0; it < NB / BLOCK; ++it) {  // 16 iterations
        const int k = threadIdx.x + it * BLOCK;
        float v = sg[mirror_idx(k + s)];
        __builtin_nontemporal_store(v, &mrow[k]);
    }
}

extern "C" void kernel_launch(void* const* d_in, const int* in_sizes, int n_in,
                              void* d_out, int out_size, void* d_ws, size_t ws_size,
                              hipStream_t stream) {
    const float* logits = (const float*)d_in[0];
    const float* u      = (const float*)d_in[1];
    const int*   shift  = (const int*)d_in[2];
    const int B = in_sizes[2];

    float* ws    = (float*)d_ws;                    // 3*NB floats
    float* masks = (float*)d_out;                   // B*NB
    float* logp  = (float*)d_out + (size_t)B * NB;  // B

    fbmp_precompute<<<(NB + 255) / 256, 256, 0, stream>>>(logits, ws);
    fbmp_main<<<B, BLOCK, 0, stream>>>(u, shift, ws, masks, logp);
}